// Round 12
// baseline (188.636 us; speedup 1.0000x reference)
//
#include <hip/hip_runtime.h>
#include <hip/hip_bf16.h>
#include <math.h>

#define SS 2048
#define HH 16
#define DD 128
#define HD (HH*DD)
#define QB 128          // q-rows per block (4 waves x 32)
#define KVB 64          // kv-tile
#define CHUNK 6         // KV tiles per job
#define NJ 51           // per-head jobs: sum_qt ceil((qt+1)/3)

typedef __attribute__((ext_vector_type(8))) short bf16x8;
typedef __attribute__((ext_vector_type(16))) float f32x16;

__device__ __forceinline__ ushort f2bf(float f) {
  __hip_bfloat16 h = __float2bfloat16(f);
  return __builtin_bit_cast(ushort, h);
}
__device__ __forceinline__ uint pk2(float a, float b) {   // low=a, high=b
  return ((uint)f2bf(b) << 16) | (uint)f2bf(a);
}
__device__ __forceinline__ float bf2f(ushort u) {
  uint x = ((uint)u) << 16;
  return __builtin_bit_cast(float, x);
}
// jobs before q-tile q: sum_{i=1..q} ceil(i/3) = 3a(a+1)/2 + b(a+1), a=q/3,b=q%3
__device__ __forceinline__ int jbase(int q) {
  int a = q / 3, b = q - 3 * a;
  return (3 * a * (a + 1)) / 2 + b * (a + 1);
}

// ---------------------------------------------------------------------------
// Flash attention, per-qt chunk jobs. Job = (h, qt, c): KV tiles
// [6c, min(6c+6, 2qt+2)). 32x32 MFMA, swapped QK^T, in-register softmax,
// O^T accumulator. Single-buffered LDS (32 KB); launch_bounds(256,3):
// VGPR cap 170 > ~150 peak need -> NO spill (R11 lesson: (256,4)=128 cap
// forced 64-VGPR + full spill). Next-tile loads issued after paf-build so
// kreg/vreg aren't live across QK^T+softmax (peak-live reduction).
// ---------------------------------------------------------------------------
__global__ __launch_bounds__(256, 3)
void attn_fwd(const float* __restrict__ Q, const float* __restrict__ K,
              const float* __restrict__ V, float* __restrict__ O,
              ushort* __restrict__ PO, float* __restrict__ PM,
              float* __restrict__ PL) {
  __shared__ alignas(16) ushort Klds[KVB * DD];    // 16 KB, swizzled
  __shared__ alignas(16) ushort VTlds[DD * KVB];   // 16 KB, swizzled

  const int tid  = threadIdx.x;
  const int lane = tid & 63;
  const int wid  = tid >> 6;       // 0..3
  const int q32  = lane & 31;
  const int hi   = lane >> 5;
  const int kxk  = (q32 & 15) << 4;                        // K read swizzle
  const int kxv  = ((q32 & 7) << 4) ^ ((q32 & 8) << 1);    // V read swizzle

  // staging decomposition
  const int g2   = (tid >> 4) & 3;   // 0..3
  const int n16  = tid & 15;         // 0..15
  const int dstg = wid * 16 + n16;   // 0..63
  const int swv  = ((dstg & 7) << 4) ^ ((dstg & 8) << 1);  // V write swizzle

  const int bx = blockIdx.x;         // 0..815
  const int h  = bx & 15;
  const int j  = bx >> 4;            // 0..50
  int qt = 0, c = 0;
  for (int q2 = 15; q2 >= 0; --q2) {
    int bq = jbase(q2);
    if (j >= bq) { qt = q2; c = j - bq; break; }
  }
  const int nt  = 2 * qt + 2;
  const int lo  = CHUNK * c;
  const int hiT = min(lo + CHUNK, nt);
  const int nc  = (qt + 3) / 3;      // chunks for this qt

  const float SCALE = 1.44269504088896f / sqrtf((float)DD);
  const float* Kb = K + (size_t)h * DD;
  const float* Vb = V + (size_t)h * DD;

  uint4 kreg[4];
  uint2 vreg[2][4];

  auto loadt = [&](int t0) {
    #pragma unroll
    for (int it = 0; it < 4; ++it) {
      int e = tid + it * 256;
      int row = e >> 4, col = (e & 15) * 8;
      const float* src = &Kb[(size_t)(t0 + row) * HD + col];
      float4 a = *(const float4*)src;
      float4 b = *(const float4*)(src + 4);
      kreg[it].x = pk2(a.x, a.y); kreg[it].y = pk2(a.z, a.w);
      kreg[it].z = pk2(b.x, b.y); kreg[it].w = pk2(b.z, b.w);
    }
    #pragma unroll
    for (int half = 0; half < 2; ++half) {
      const int d = dstg + 64 * half;
      #pragma unroll
      for (int jv = 0; jv < 4; ++jv) {
        const int tt = 16 * jv + 4 * g2;
        const float* vp = &Vb[(size_t)(t0 + tt) * HD + d];
        vreg[half][jv].x = pk2(vp[0],      vp[HD]);
        vreg[half][jv].y = pk2(vp[2 * HD], vp[3 * HD]);
      }
    }
  };
  auto staget = [&]() {
    #pragma unroll
    for (int it = 0; it < 4; ++it) {
      int e = tid + it * 256;
      *(uint4*)((char*)Klds + ((e * 16) ^ (e & 0xF0))) = kreg[it];
    }
    #pragma unroll
    for (int half = 0; half < 2; ++half) {
      const int d = dstg + 64 * half;
      #pragma unroll
      for (int jv = 0; jv < 4; ++jv) {
        const int tt = 16 * jv + 4 * g2;
        *(uint2*)((char*)VTlds + ((d * 128 + tt * 2) ^ swv)) = vreg[half][jv];
      }
    }
  };

  const int qw = qt * QB + 32 * wid;   // wave's first q row
  const int qg = qw + q32;             // this lane's q row

  // ---- Q fragments (B operand): qf[ks] = Q[qg][16ks+8hi+0..7] * SCALE ----
  bf16x8 qf[8];
  {
    const float* qr = Q + ((size_t)qg * HH + h) * DD;
    #pragma unroll
    for (int ks = 0; ks < 8; ++ks) {
      float4 x = *(const float4*)&qr[16 * ks + 8 * hi];
      float4 y = *(const float4*)&qr[16 * ks + 8 * hi + 4];
      uint4 u;
      u.x = pk2(x.x * SCALE, x.y * SCALE);
      u.y = pk2(x.z * SCALE, x.w * SCALE);
      u.z = pk2(y.x * SCALE, y.y * SCALE);
      u.w = pk2(y.z * SCALE, y.w * SCALE);
      qf[ks] = __builtin_bit_cast(bf16x8, u);
    }
  }

  f32x16 acc[4];
  #pragma unroll
  for (int dt = 0; dt < 4; ++dt)
    #pragma unroll
    for (int e = 0; e < 16; ++e) acc[dt][e] = 0.f;
  float m = -1e30f, l = 0.f;

  // ---- prologue ----
  loadt(lo * KVB);
  staget();

  for (int itile = lo; itile < hiT; ++itile) {
    __syncthreads();             // staged tile visible
    const bool more = (itile + 1 < hiT);

    const int t0 = itile * KVB;
    const char* Kc = (const char*)Klds;
    const char* Vc = (const char*)VTlds;

    // ---- QK^T swapped, s0/s1 interleaved ----
    f32x16 s0, s1;
    #pragma unroll
    for (int e = 0; e < 16; ++e) { s0[e] = 0.f; s1[e] = 0.f; }
    __builtin_amdgcn_s_setprio(1);
    #pragma unroll
    for (int ks = 0; ks < 8; ++ks) {
      bf16x8 a0 = *(const bf16x8*)(Kc + ((q32 * 256 + 32 * ks + 16 * hi) ^ kxk));
      s0 = __builtin_amdgcn_mfma_f32_32x32x16_bf16(a0, qf[ks], s0, 0, 0, 0);
      bf16x8 a1 = *(const bf16x8*)(Kc + (((q32 + 32) * 256 + 32 * ks + 16 * hi) ^ kxk));
      s1 = __builtin_amdgcn_mfma_f32_32x32x16_bf16(a1, qf[ks], s1, 0, 0, 0);
    }
    __builtin_amdgcn_s_setprio(0);

    // ---- causal mask ----
    if (t0 + KVB - 1 > qw) {
      #pragma unroll
      for (int e = 0; e < 16; ++e) {
        int tloc = (e & 3) + 8 * (e >> 2) + 4 * hi;
        if (t0 + tloc > qg)      s0[e] = -INFINITY;
        if (t0 + 32 + tloc > qg) s1[e] = -INFINITY;
      }
    }

    // ---- online softmax: tree reductions + defer-max ----
    float tmx[8];
    #pragma unroll
    for (int e = 0; e < 8; ++e)
      tmx[e] = fmaxf(fmaxf(s0[e], s0[e + 8]), fmaxf(s1[e], s1[e + 8]));
    #pragma unroll
    for (int st = 4; st >= 1; st >>= 1)
      #pragma unroll
      for (int e = 0; e < st; ++e) tmx[e] = fmaxf(tmx[e], tmx[e + st]);
    float mr = fmaxf(tmx[0], __shfl_xor(tmx[0], 32));

    if (!__all(mr <= m + 8.0f)) {
      float mn = fmaxf(m, mr);
      float corr = exp2f(m - mn);
      m = mn;
      l *= corr;
      #pragma unroll
      for (int dt = 0; dt < 4; ++dt)
        #pragma unroll
        for (int e = 0; e < 16; ++e) acc[dt][e] *= corr;
    }

    float ts[8];
    #pragma unroll
    for (int e = 0; e < 8; ++e) ts[e] = 0.f;
    #pragma unroll
    for (int e = 0; e < 16; ++e) {
      float p0 = exp2f(s0[e] - m); s0[e] = p0;
      float p1 = exp2f(s1[e] - m); s1[e] = p1;
      ts[e & 7] += p0 + p1;
    }
    #pragma unroll
    for (int st = 4; st >= 1; st >>= 1)
      #pragma unroll
      for (int e = 0; e < st; ++e) ts[e] += ts[e + st];
    float ps = ts[0] + __shfl_xor(ts[0], 32);
    l += ps;

    // ---- P -> bf16 B-fragments (cvt_pk pairs + lane<->lane+32 exchange) ----
    uint4 paf[4];
    #pragma unroll
    for (int tk = 0; tk < 4; ++tk) {
      float p0,p1,p2,p3,p4,p5,p6,p7;
      if (tk == 0) { p0=s0[0];p1=s0[1];p2=s0[2];p3=s0[3];p4=s0[4];p5=s0[5];p6=s0[6];p7=s0[7]; }
      else if (tk == 1) { p0=s0[8];p1=s0[9];p2=s0[10];p3=s0[11];p4=s0[12];p5=s0[13];p6=s0[14];p7=s0[15]; }
      else if (tk == 2) { p0=s1[0];p1=s1[1];p2=s1[2];p3=s1[3];p4=s1[4];p5=s1[5];p6=s1[6];p7=s1[7]; }
      else { p0=s1[8];p1=s1[9];p2=s1[10];p3=s1[11];p4=s1[12];p5=s1[13];p6=s1[14];p7=s1[15]; }
      uint A0 = pk2(p0, p1), A1 = pk2(p2, p3);
      uint B0 = pk2(p4, p5), B1 = pk2(p6, p7);
      uint x0 = hi ? A0 : B0, x1 = hi ? A1 : B1;
      uint r0 = (uint)__shfl_xor((int)x0, 32);
      uint r1 = (uint)__shfl_xor((int)x1, 32);
      paf[tk].x = hi ? r0 : A0;
      paf[tk].y = hi ? r1 : A1;
      paf[tk].z = hi ? B0 : r0;
      paf[tk].w = hi ? B1 : r1;
    }

    // ---- issue next-tile loads here: kreg/vreg live only across PV ----
    if (more) loadt((itile + 1) * KVB);

    // ---- PV: tk outer / dt inner ----
    __builtin_amdgcn_s_setprio(1);
    #pragma unroll
    for (int tk = 0; tk < 4; ++tk) {
      bf16x8 pb = __builtin_bit_cast(bf16x8, paf[tk]);
      #pragma unroll
      for (int dt = 0; dt < 4; ++dt) {
        bf16x8 va = *(const bf16x8*)(Vc +
                      (((dt * 32 + q32) * 128 + 32 * tk + 16 * hi) ^ kxv));
        acc[dt] = __builtin_amdgcn_mfma_f32_32x32x16_bf16(va, pb, acc[dt], 0, 0, 0);
      }
    }
    __builtin_amdgcn_s_setprio(0);

    __syncthreads();             // all LDS reads of this tile done
    if (more) staget();          // write next tile into the single buffer
  }

  // ---- epilogue ----
  const int row = 32 * wid + q32;
  if (nc == 1) {
    // qt <= 2: only chunk -> normalize and write O directly
    float invl = 1.0f / l;
    float* op = O + ((size_t)(qt * QB + row) * HH + h) * DD;
    #pragma unroll
    for (int dt = 0; dt < 4; ++dt) {
      #pragma unroll
      for (int rq = 0; rq < 4; ++rq) {
        int d = 32 * dt + 8 * rq + 4 * hi;
        float4 x = make_float4(acc[dt][4 * rq + 0] * invl, acc[dt][4 * rq + 1] * invl,
                               acc[dt][4 * rq + 2] * invl, acc[dt][4 * rq + 3] * invl);
        *(float4*)&op[d] = x;
      }
    }
  } else {
    ushort* po = PO + (size_t)bx * (QB * DD);
    #pragma unroll
    for (int dt = 0; dt < 4; ++dt) {
      #pragma unroll
      for (int rq = 0; rq < 4; ++rq) {
        int d = 32 * dt + 8 * rq + 4 * hi;
        uint2 w;
        w.x = pk2(acc[dt][4 * rq + 0], acc[dt][4 * rq + 1]);
        w.y = pk2(acc[dt][4 * rq + 2], acc[dt][4 * rq + 3]);
        *(uint2*)&po[row * DD + d] = w;
      }
    }
    if (hi == 0) {
      PM[(size_t)bx * QB + row] = m;
      PL[(size_t)bx * QB + row] = l;
    }
  }
}

// ---------------------------------------------------------------------------
// Merge 2-6 partials per (h, qt) for qt >= 3. Two-pass (no runtime-indexed
// register arrays -> no scratch).
// ---------------------------------------------------------------------------
__global__ __launch_bounds__(256, 2)
void attn_merge(const ushort* __restrict__ PO, const float* __restrict__ PM,
                const float* __restrict__ PL, float* __restrict__ O) {
  const int bx  = blockIdx.x;      // 208 = 13 qt * 16 h
  const int h   = bx & 15;
  const int qt  = 3 + (bx >> 4);   // 3..15
  const int tid = threadIdx.x;
  const int r   = tid >> 1;        // 0..127
  const int dh  = (tid & 1) * 64;

  const int base = jbase(qt);
  const int nc   = (qt + 3) / 3;

  float M = -1e30f;
  for (int cc = 0; cc < nc; ++cc) {
    int slot = (base + cc) * 16 + h;
    M = fmaxf(M, PM[(size_t)slot * QB + r]);
  }
  float L = 0.f;
  float o[64];
  #pragma unroll
  for (int k2 = 0; k2 < 64; ++k2) o[k2] = 0.f;
  for (int cc = 0; cc < nc; ++cc) {
    int slot = (base + cc) * 16 + h;
    float w = exp2f(PM[(size_t)slot * QB + r] - M);
    L += PL[(size_t)slot * QB + r] * w;
    const ushort* src = PO + (size_t)slot * (QB * DD) + r * DD + dh;
    #pragma unroll
    for (int k4 = 0; k4 < 16; ++k4) {
      ushort4 u = *(const ushort4*)&src[4 * k4];
      o[4*k4+0] += bf2f(u.x) * w;
      o[4*k4+1] += bf2f(u.y) * w;
      o[4*k4+2] += bf2f(u.z) * w;
      o[4*k4+3] += bf2f(u.w) * w;
    }
  }
  float inv = 1.0f / L;
  float* op = O + ((size_t)(qt * QB + r) * HH + h) * DD + dh;
  #pragma unroll
  for (int k4 = 0; k4 < 16; ++k4) {
    float4 x = make_float4(o[4*k4]*inv, o[4*k4+1]*inv, o[4*k4+2]*inv, o[4*k4+3]*inv);
    *(float4*)&op[4 * k4] = x;
  }
}

extern "C" void kernel_launch(void* const* d_in, const int* in_sizes, int n_in,
                              void* d_out, int out_size, void* d_ws, size_t ws_size,
                              hipStream_t stream) {
  const float* Q = (const float*)d_in[0];
  const float* K = (const float*)d_in[1];
  const float* V = (const float*)d_in[2];
  float* O = (float*)d_out;

  const size_t po_elems = (size_t)(NJ * 16) * QB * DD;   // 816*16384 bf16 = 25.5 MB
  ushort* PO = (ushort*)d_ws;
  float*  PM = (float*)(PO + po_elems);                  // 816*128 f32
  float*  PL = PM + (size_t)(NJ * 16) * QB;

  attn_fwd<<<dim3(NJ * 16), 256, 0, stream>>>(Q, K, V, O, PO, PM, PL);
  attn_merge<<<dim3(13 * 16), 256, 0, stream>>>(PO, PM, PL, O);
}

// Round 13
// 84.527 us; speedup vs baseline: 2.2317x; 2.2317x over previous
//
#include <hip/hip_runtime.h>
#include <hip/hip_bf16.h>
#include <math.h>

#define SS 2048
#define HH 16
#define DD 128
#define HD (HH*DD)
#define QB 128          // q-rows per block (4 waves x 32)
#define KVB 64          // kv-tile
#define CHUNK 7         // KV tiles per job
#define NJ 46           // per-head jobs (JB[16])

typedef __attribute__((ext_vector_type(8))) short bf16x8;
typedef __attribute__((ext_vector_type(16))) float f32x16;

__device__ __forceinline__ ushort f2bf(float f) {
  __hip_bfloat16 h = __float2bfloat16(f);
  return __builtin_bit_cast(ushort, h);
}
__device__ __forceinline__ uint pk2(float a, float b) {   // low=a, high=b
  return ((uint)f2bf(b) << 16) | (uint)f2bf(a);
}
__device__ __forceinline__ float bf2f(ushort u) {
  uint x = ((uint)u) << 16;
  return __builtin_bit_cast(float, x);
}
__device__ __forceinline__ void gld16(const void* g, void* l) {
  __builtin_amdgcn_global_load_lds(
      (const __attribute__((address_space(1))) void*)g,
      (__attribute__((address_space(3))) void*)l, 16, 0, 0);
}

// chunks(q) = ceil((2q+2)/7); JB = prefix sums
__constant__ const int JBc[17] = {0,1,2,3,5,7,9,11,14,17,20,24,28,32,36,41,46};

// ---------------------------------------------------------------------------
// Prep: K fp32 [t][h][d] -> bf16 Kbf [h][t][d]
//       V fp32 [t][h][d] -> bf16 VTg [h][tc][d][t']  (tile-blocked transpose)
// ---------------------------------------------------------------------------
__global__ __launch_bounds__(256, 4)
void prep_kv(const float* __restrict__ K, const float* __restrict__ V,
             ushort* __restrict__ Kbf, ushort* __restrict__ VTg) {
  __shared__ ushort Vlds[64][136];
  const int tid = threadIdx.x;
  const int h  = blockIdx.x & 15;
  const int tc = blockIdx.x >> 4;
  const int t0 = tc * 64;

  #pragma unroll
  for (int j = 0; j < 2; ++j) {
    int li = tid + j * 256;
    int t  = li >> 3;
    int c  = (li & 7) << 4;
    const float* src = K + ((size_t)(t0 + t) * HH + h) * DD + c;
    ushort tmp[16];
    #pragma unroll
    for (int q = 0; q < 4; ++q) {
      float4 x = *(const float4*)(src + 4 * q);
      tmp[4*q+0] = f2bf(x.x); tmp[4*q+1] = f2bf(x.y);
      tmp[4*q+2] = f2bf(x.z); tmp[4*q+3] = f2bf(x.w);
    }
    ushort* dst = Kbf + ((size_t)h * SS + t0 + t) * DD + c;
    *(uint4*)dst       = *(uint4*)&tmp[0];
    *(uint4*)(dst + 8) = *(uint4*)&tmp[8];
  }

  #pragma unroll
  for (int j = 0; j < 2; ++j) {
    int li = tid + j * 256;
    int t  = li >> 3;
    int c  = (li & 7) << 4;
    const float* src = V + ((size_t)(t0 + t) * HH + h) * DD + c;
    #pragma unroll
    for (int q = 0; q < 4; ++q) {
      float4 x = *(const float4*)(src + 4 * q);
      ushort4 w; w.x = f2bf(x.x); w.y = f2bf(x.y); w.z = f2bf(x.z); w.w = f2bf(x.w);
      *(ushort4*)&Vlds[t][c + 4 * q] = w;
    }
  }
  __syncthreads();

  #pragma unroll
  for (int j = 0; j < 2; ++j) {
    int li  = tid + j * 256;
    int d   = li >> 2;
    int t16 = (li & 3) << 4;
    ushort tmp[16];
    #pragma unroll
    for (int k = 0; k < 16; ++k) tmp[k] = Vlds[t16 + k][d];
    ushort* dst = VTg + (((size_t)h * 32 + tc) * DD + d) * 64 + t16;
    *(uint4*)dst       = *(uint4*)&tmp[0];
    *(uint4*)(dst + 8) = *(uint4*)&tmp[8];
  }
}

// ---------------------------------------------------------------------------
// Flash attention. Job = (h, qt, c): KV tiles [7c, min(7c+7, 2qt+2)).
// 32x32 MFMA, swapped QK^T, in-register softmax, O^T accumulator.
// Staging: global_load_lds w=16 from pre-converted bf16, source pre-swizzled
// (rule 21: linear LDS dest + inverse-swizzled global source; reads keep
// the R10-verified XOR patterns). K double-buffered, V single. 48 KB LDS,
// launch_bounds(256,3): reg need ~150 <= 168 cap (R11/R12 lesson: cap is
// (VGPR+AGPR) <= 512/waves-per-SIMD; staging regs deleted to fit).
// ---------------------------------------------------------------------------
__global__ __launch_bounds__(256, 3)
void attn_fwd(const float* __restrict__ Q, const ushort* __restrict__ Kbf,
              const ushort* __restrict__ VTg, float* __restrict__ O,
              ushort* __restrict__ PO, float* __restrict__ PM,
              float* __restrict__ PL) {
  __shared__ alignas(16) ushort Klds[2][KVB * DD];   // 2 x 16 KB
  __shared__ alignas(16) ushort VTlds[DD * KVB];     // 16 KB

  const int tid  = threadIdx.x;
  const int lane = tid & 63;
  const int wid  = tid >> 6;       // 0..3
  const int q32  = lane & 31;
  const int hi   = lane >> 5;
  const int kxk  = (q32 & 15) << 4;                        // K read swizzle
  const int kxv  = ((q32 & 7) << 4) ^ ((q32 & 8) << 1);    // V read swizzle

  // DMA per-lane source offsets (pre-swizzle), LDS-uniform bases
  int koff[4], voff[4];
  #pragma unroll
  for (int k2 = 0; k2 < 4; ++k2) {
    int b = wid * 4096 + k2 * 1024 + 16 * lane;
    int krow = b >> 8;                                   // K row (256 B rows)
    koff[k2] = b ^ ((krow & 15) << 4);
    int d = b >> 7;                                      // V row (128 B rows)
    voff[k2] = b ^ (((d & 7) << 4) ^ ((d & 8) << 1));
  }

  const int bx = blockIdx.x;         // 0..735
  const int h  = bx & 15;
  const int j  = bx >> 4;            // 0..45
  int qt = 0, c = 0;
  #pragma unroll
  for (int q2 = 15; q2 >= 0; --q2) {
    if (j >= JBc[q2]) { qt = q2; c = j - JBc[q2]; break; }
  }
  const int nt  = 2 * qt + 2;
  const int lo  = CHUNK * c;
  const int hiT = min(lo + CHUNK, nt);
  const int nc  = JBc[qt + 1] - JBc[qt];

  const float SCALE = 1.44269504088896f / sqrtf((float)DD);
  const char* KG = (const char*)Kbf + (size_t)h * SS * DD * 2;   // [t][d] bf16
  const char* VG = (const char*)VTg + (size_t)h * 32 * 16384;    // [tc][d][t']

  auto issueK = [&](int t0, int buf) {
    const char* gt = KG + (size_t)t0 * 256;
    char* lb = (char*)&Klds[buf][0] + wid * 4096;
    #pragma unroll
    for (int k2 = 0; k2 < 4; ++k2)
      gld16(gt + koff[k2], lb + k2 * 1024);
  };
  auto issueV = [&](int tc) {
    const char* gt = VG + (size_t)tc * 16384;
    char* lb = (char*)VTlds + wid * 4096;
    #pragma unroll
    for (int k2 = 0; k2 < 4; ++k2)
      gld16(gt + voff[k2], lb + k2 * 1024);
  };

  const int qw = qt * QB + 32 * wid;   // wave's first q row
  const int qg = qw + q32;             // this lane's q row

  // ---- Q fragments (B operand): qf[ks] = Q[qg][16ks+8hi+0..7] * SCALE ----
  bf16x8 qf[8];
  {
    const float* qr = Q + ((size_t)qg * HH + h) * DD;
    #pragma unroll
    for (int ks = 0; ks < 8; ++ks) {
      float4 x = *(const float4*)&qr[16 * ks + 8 * hi];
      float4 y = *(const float4*)&qr[16 * ks + 8 * hi + 4];
      uint4 u;
      u.x = pk2(x.x * SCALE, x.y * SCALE);
      u.y = pk2(x.z * SCALE, x.w * SCALE);
      u.z = pk2(y.x * SCALE, y.y * SCALE);
      u.w = pk2(y.z * SCALE, y.w * SCALE);
      qf[ks] = __builtin_bit_cast(bf16x8, u);
    }
  }

  f32x16 acc[4];
  #pragma unroll
  for (int dt = 0; dt < 4; ++dt)
    #pragma unroll
    for (int e = 0; e < 16; ++e) acc[dt][e] = 0.f;
  float m = -1e30f, l = 0.f;

  // ---- prologue: DMA tile lo ----
  issueK(lo * KVB, 0);
  issueV(lo);
  int cur = 0;

  for (int itile = lo; itile < hiT; ++itile) {
    __syncthreads();             // drains vmcnt -> K[cur],V resident; syncs readers
    const bool more = (itile + 1 < hiT);
    if (more) issueK((itile + 1) * KVB, cur ^ 1);   // overlaps all compute below

    const int t0 = itile * KVB;
    const char* Kc = (const char*)&Klds[cur][0];
    const char* Vc = (const char*)VTlds;

    // ---- QK^T swapped, s0/s1 interleaved ----
    f32x16 s0, s1;
    #pragma unroll
    for (int e = 0; e < 16; ++e) { s0[e] = 0.f; s1[e] = 0.f; }
    __builtin_amdgcn_s_setprio(1);
    #pragma unroll
    for (int ks = 0; ks < 8; ++ks) {
      bf16x8 a0 = *(const bf16x8*)(Kc + ((q32 * 256 + 32 * ks + 16 * hi) ^ kxk));
      s0 = __builtin_amdgcn_mfma_f32_32x32x16_bf16(a0, qf[ks], s0, 0, 0, 0);
      bf16x8 a1 = *(const bf16x8*)(Kc + (((q32 + 32) * 256 + 32 * ks + 16 * hi) ^ kxk));
      s1 = __builtin_amdgcn_mfma_f32_32x32x16_bf16(a1, qf[ks], s1, 0, 0, 0);
    }
    __builtin_amdgcn_s_setprio(0);

    // ---- causal mask ----
    if (t0 + KVB - 1 > qw) {
      #pragma unroll
      for (int e = 0; e < 16; ++e) {
        int tloc = (e & 3) + 8 * (e >> 2) + 4 * hi;
        if (t0 + tloc > qg)      s0[e] = -INFINITY;
        if (t0 + 32 + tloc > qg) s1[e] = -INFINITY;
      }
    }

    // ---- online softmax: tree reductions + defer-max ----
    float tmx[8];
    #pragma unroll
    for (int e = 0; e < 8; ++e)
      tmx[e] = fmaxf(fmaxf(s0[e], s0[e + 8]), fmaxf(s1[e], s1[e + 8]));
    #pragma unroll
    for (int st = 4; st >= 1; st >>= 1)
      #pragma unroll
      for (int e = 0; e < st; ++e) tmx[e] = fmaxf(tmx[e], tmx[e + st]);
    float mr = fmaxf(tmx[0], __shfl_xor(tmx[0], 32));

    if (!__all(mr <= m + 8.0f)) {
      float mn = fmaxf(m, mr);
      float corr = exp2f(m - mn);
      m = mn;
      l *= corr;
      #pragma unroll
      for (int dt = 0; dt < 4; ++dt)
        #pragma unroll
        for (int e = 0; e < 16; ++e) acc[dt][e] *= corr;
    }

    float ts[8];
    #pragma unroll
    for (int e = 0; e < 8; ++e) ts[e] = 0.f;
    #pragma unroll
    for (int e = 0; e < 16; ++e) {
      float p0 = exp2f(s0[e] - m); s0[e] = p0;
      float p1 = exp2f(s1[e] - m); s1[e] = p1;
      ts[e & 7] += p0 + p1;
    }
    #pragma unroll
    for (int st = 4; st >= 1; st >>= 1)
      #pragma unroll
      for (int e = 0; e < st; ++e) ts[e] += ts[e + st];
    float ps = ts[0] + __shfl_xor(ts[0], 32);
    l += ps;

    // ---- P -> bf16 B-fragments (cvt_pk pairs + lane<->lane+32 exchange) ----
    uint4 paf[4];
    #pragma unroll
    for (int tk = 0; tk < 4; ++tk) {
      float p0,p1,p2,p3,p4,p5,p6,p7;
      if (tk == 0) { p0=s0[0];p1=s0[1];p2=s0[2];p3=s0[3];p4=s0[4];p5=s0[5];p6=s0[6];p7=s0[7]; }
      else if (tk == 1) { p0=s0[8];p1=s0[9];p2=s0[10];p3=s0[11];p4=s0[12];p5=s0[13];p6=s0[14];p7=s0[15]; }
      else if (tk == 2) { p0=s1[0];p1=s1[1];p2=s1[2];p3=s1[3];p4=s1[4];p5=s1[5];p6=s1[6];p7=s1[7]; }
      else { p0=s1[8];p1=s1[9];p2=s1[10];p3=s1[11];p4=s1[12];p5=s1[13];p6=s1[14];p7=s1[15]; }
      uint A0 = pk2(p0, p1), A1 = pk2(p2, p3);
      uint B0 = pk2(p4, p5), B1 = pk2(p6, p7);
      uint x0 = hi ? A0 : B0, x1 = hi ? A1 : B1;
      uint r0 = (uint)__shfl_xor((int)x0, 32);
      uint r1 = (uint)__shfl_xor((int)x1, 32);
      paf[tk].x = hi ? r0 : A0;
      paf[tk].y = hi ? r1 : A1;
      paf[tk].z = hi ? B0 : r0;
      paf[tk].w = hi ? B1 : r1;
    }

    // ---- PV: tk outer / dt inner ----
    __builtin_amdgcn_s_setprio(1);
    #pragma unroll
    for (int tk = 0; tk < 4; ++tk) {
      bf16x8 pb = __builtin_bit_cast(bf16x8, paf[tk]);
      #pragma unroll
      for (int dt = 0; dt < 4; ++dt) {
        bf16x8 va = *(const bf16x8*)(Vc +
                      (((dt * 32 + q32) * 128 + 32 * tk + 16 * hi) ^ kxv));
        acc[dt] = __builtin_amdgcn_mfma_f32_32x32x16_bf16(va, pb, acc[dt], 0, 0, 0);
      }
    }
    __builtin_amdgcn_s_setprio(0);

    __syncthreads();             // all LDS reads of this tile done
    if (more) issueV(itile + 1); // refill single V buffer
    cur ^= 1;
  }

  // ---- epilogue ----
  const int row = 32 * wid + q32;
  if (nc == 1) {
    float invl = 1.0f / l;
    float* op = O + ((size_t)(qt * QB + row) * HH + h) * DD;
    #pragma unroll
    for (int dt = 0; dt < 4; ++dt) {
      #pragma unroll
      for (int rq = 0; rq < 4; ++rq) {
        int d = 32 * dt + 8 * rq + 4 * hi;
        float4 x = make_float4(acc[dt][4 * rq + 0] * invl, acc[dt][4 * rq + 1] * invl,
                               acc[dt][4 * rq + 2] * invl, acc[dt][4 * rq + 3] * invl);
        *(float4*)&op[d] = x;
      }
    }
  } else {
    ushort* po = PO + (size_t)bx * (QB * DD);
    #pragma unroll
    for (int dt = 0; dt < 4; ++dt) {
      #pragma unroll
      for (int rq = 0; rq < 4; ++rq) {
        int d = 32 * dt + 8 * rq + 4 * hi;
        uint2 w;
        w.x = pk2(acc[dt][4 * rq + 0], acc[dt][4 * rq + 1]);
        w.y = pk2(acc[dt][4 * rq + 2], acc[dt][4 * rq + 3]);
        *(uint2*)&po[row * DD + d] = w;
      }
    }
    if (hi == 0) {
      PM[(size_t)bx * QB + row] = m;
      PL[(size_t)bx * QB + row] = l;
    }
  }
}

// ---------------------------------------------------------------------------
// Merge 2-5 partials per (h, qt) for qt >= 3.
// ---------------------------------------------------------------------------
__global__ __launch_bounds__(256, 2)
void attn_merge(const ushort* __restrict__ PO, const float* __restrict__ PM,
                const float* __restrict__ PL, float* __restrict__ O) {
  const int bx  = blockIdx.x;      // 208 = 13 qt * 16 h
  const int h   = bx & 15;
  const int qt  = 3 + (bx >> 4);   // 3..15
  const int tid = threadIdx.x;
  const int r   = tid >> 1;        // 0..127
  const int dh  = (tid & 1) * 64;

  const int base = JBc[qt];
  const int nc   = JBc[qt + 1] - JBc[qt];

  float M = -1e30f;
  for (int cc = 0; cc < nc; ++cc) {
    int slot = (base + cc) * 16 + h;
    M = fmaxf(M, PM[(size_t)slot * QB + r]);
  }
  float L = 0.f;
  float o[64];
  #pragma unroll
  for (int k2 = 0; k2 < 64; ++k2) o[k2] = 0.f;
  for (int cc = 0; cc < nc; ++cc) {
    int slot = (base + cc) * 16 + h;
    float w = exp2f(PM[(size_t)slot * QB + r] - M);
    L += PL[(size_t)slot * QB + r] * w;
    const ushort* src = PO + (size_t)slot * (QB * DD) + r * DD + dh;
    #pragma unroll
    for (int k4 = 0; k4 < 16; ++k4) {
      ushort4 u = *(const ushort4*)&src[4 * k4];
      o[4*k4+0] += bf2f(u.x) * w;
      o[4*k4+1] += bf2f(u.y) * w;
      o[4*k4+2] += bf2f(u.z) * w;
      o[4*k4+3] += bf2f(u.w) * w;
    }
  }
  float inv = 1.0f / L;
  float* op = O + ((size_t)(qt * QB + r) * HH + h) * DD + dh;
  #pragma unroll
  for (int k4 = 0; k4 < 16; ++k4) {
    float4 x = make_float4(o[4*k4]*inv, o[4*k4+1]*inv, o[4*k4+2]*inv, o[4*k4+3]*inv);
    *(float4*)&op[4 * k4] = x;
  }
}

extern "C" void kernel_launch(void* const* d_in, const int* in_sizes, int n_in,
                              void* d_out, int out_size, void* d_ws, size_t ws_size,
                              hipStream_t stream) {
  const float* Q = (const float*)d_in[0];
  const float* K = (const float*)d_in[1];
  const float* V = (const float*)d_in[2];
  float* O = (float*)d_out;

  const size_t kv_elems = (size_t)HH * SS * DD;          // 4,194,304 ushorts each
  ushort* Kbf = (ushort*)d_ws;                           // 8.4 MB
  ushort* VTg = Kbf + kv_elems;                          // 8.4 MB
  ushort* PO  = VTg + kv_elems;                          // 736*16384 bf16 = 24.1 MB
  float*  PM  = (float*)(PO + (size_t)(NJ * 16) * QB * DD);
  float*  PL  = PM + (size_t)(NJ * 16) * QB;

  prep_kv<<<dim3(HH * (SS / 64)), 256, 0, stream>>>(K, V, Kbf, VTg);
  attn_fwd<<<dim3(NJ * 16), 256, 0, stream>>>(Q, Kbf, VTg, O, PO, PM, PL);
  attn_merge<<<dim3(13 * 16), 256, 0, stream>>>(PO, PM, PL, O);
}

// Round 14
// 78.661 us; speedup vs baseline: 2.3981x; 1.0746x over previous
//
#include <hip/hip_runtime.h>
#include <hip/hip_bf16.h>
#include <math.h>

#define SS 2048
#define HH 16
#define DD 128
#define HD (HH*DD)
#define QB 128          // q-rows per block (4 waves x 32)
#define KVB 64          // kv-tile
#define CHUNK 7         // KV tiles per job
#define NJ 46           // per-head jobs (JB[16])

typedef __attribute__((ext_vector_type(8))) short bf16x8;
typedef __attribute__((ext_vector_type(16))) float f32x16;

__device__ __forceinline__ ushort f2bf(float f) {
  __hip_bfloat16 h = __float2bfloat16(f);
  return __builtin_bit_cast(ushort, h);
}
__device__ __forceinline__ uint pk2(float a, float b) {   // low=a, high=b
  return ((uint)f2bf(b) << 16) | (uint)f2bf(a);
}
__device__ __forceinline__ float bf2f(ushort u) {
  uint x = ((uint)u) << 16;
  return __builtin_bit_cast(float, x);
}
__device__ __forceinline__ void gld16(const void* g, void* l) {
  __builtin_amdgcn_global_load_lds(
      (const __attribute__((address_space(1))) void*)g,
      (__attribute__((address_space(3))) void*)l, 16, 0, 0);
}

// chunks(q) = ceil((2q+2)/7); JB = prefix sums
__constant__ const int JBc[17] = {0,1,2,3,5,7,9,11,14,17,20,24,28,32,36,41,46};

// ---------------------------------------------------------------------------
// Prep: K fp32 [t][h][d] -> bf16 Kbf [h][t][d]
//       V fp32 [t][h][d] -> bf16 VTg [h][tc][d][t']  (tile-blocked transpose)
// ---------------------------------------------------------------------------
__global__ __launch_bounds__(256, 4)
void prep_kv(const float* __restrict__ K, const float* __restrict__ V,
             ushort* __restrict__ Kbf, ushort* __restrict__ VTg) {
  __shared__ ushort Vlds[64][136];
  const int tid = threadIdx.x;
  const int h  = blockIdx.x & 15;
  const int tc = blockIdx.x >> 4;
  const int t0 = tc * 64;

  #pragma unroll
  for (int j = 0; j < 2; ++j) {
    int li = tid + j * 256;
    int t  = li >> 3;
    int c  = (li & 7) << 4;
    const float* src = K + ((size_t)(t0 + t) * HH + h) * DD + c;
    ushort tmp[16];
    #pragma unroll
    for (int q = 0; q < 4; ++q) {
      float4 x = *(const float4*)(src + 4 * q);
      tmp[4*q+0] = f2bf(x.x); tmp[4*q+1] = f2bf(x.y);
      tmp[4*q+2] = f2bf(x.z); tmp[4*q+3] = f2bf(x.w);
    }
    ushort* dst = Kbf + ((size_t)h * SS + t0 + t) * DD + c;
    *(uint4*)dst       = *(uint4*)&tmp[0];
    *(uint4*)(dst + 8) = *(uint4*)&tmp[8];
  }

  #pragma unroll
  for (int j = 0; j < 2; ++j) {
    int li = tid + j * 256;
    int t  = li >> 3;
    int c  = (li & 7) << 4;
    const float* src = V + ((size_t)(t0 + t) * HH + h) * DD + c;
    #pragma unroll
    for (int q = 0; q < 4; ++q) {
      float4 x = *(const float4*)(src + 4 * q);
      ushort4 w; w.x = f2bf(x.x); w.y = f2bf(x.y); w.z = f2bf(x.z); w.w = f2bf(x.w);
      *(ushort4*)&Vlds[t][c + 4 * q] = w;
    }
  }
  __syncthreads();

  #pragma unroll
  for (int j = 0; j < 2; ++j) {
    int li  = tid + j * 256;
    int d   = li >> 2;
    int t16 = (li & 3) << 4;
    ushort tmp[16];
    #pragma unroll
    for (int k = 0; k < 16; ++k) tmp[k] = Vlds[t16 + k][d];
    ushort* dst = VTg + (((size_t)h * 32 + tc) * DD + d) * 64 + t16;
    *(uint4*)dst       = *(uint4*)&tmp[0];
    *(uint4*)(dst + 8) = *(uint4*)&tmp[8];
  }
}

// ---------------------------------------------------------------------------
// Flash attention. Job = (h, qt, c): KV tiles [7c, min(7c+7, 2qt+2)).
// 32x32 MFMA, swapped QK^T, in-register softmax, O^T accumulator.
// Staging: global_load_lds w=16 from pre-converted bf16, pre-swizzled
// source offsets (rule 21). K AND V double-buffered (64 KB LDS) -> ONE
// barrier per tile; next-tile DMAs issue right after the barrier and
// overlap all compute. launch_bounds(256,2): reg need ~185 fits the 256
// cap -> NO spill (R11/R12/R13 law: tighter bounds trade spill for
// occupancy at a net loss; this kernel is a 2-blocks/CU design).
// ---------------------------------------------------------------------------
__global__ __launch_bounds__(256, 2)
void attn_fwd(const float* __restrict__ Q, const ushort* __restrict__ Kbf,
              const ushort* __restrict__ VTg, float* __restrict__ O,
              ushort* __restrict__ PO, float* __restrict__ PM,
              float* __restrict__ PL) {
  __shared__ alignas(16) ushort Klds[2][KVB * DD];   // 2 x 16 KB
  __shared__ alignas(16) ushort VTlds[2][DD * KVB];  // 2 x 16 KB

  const int tid  = threadIdx.x;
  const int lane = tid & 63;
  const int wid  = tid >> 6;       // 0..3
  const int q32  = lane & 31;
  const int hi   = lane >> 5;
  const int kxk  = (q32 & 15) << 4;                        // K read swizzle
  const int kxv  = ((q32 & 7) << 4) ^ ((q32 & 8) << 1);    // V read swizzle

  // DMA per-lane source offsets (pre-swizzle), LDS-uniform bases
  int koff[4], voff[4];
  #pragma unroll
  for (int k2 = 0; k2 < 4; ++k2) {
    int b = wid * 4096 + k2 * 1024 + 16 * lane;
    int krow = b >> 8;                                   // K row (256 B rows)
    koff[k2] = b ^ ((krow & 15) << 4);
    int d = b >> 7;                                      // V row (128 B rows)
    voff[k2] = b ^ (((d & 7) << 4) ^ ((d & 8) << 1));
  }

  const int bx = blockIdx.x;         // 0..735
  const int h  = bx & 15;
  const int j  = bx >> 4;            // 0..45
  int qt = 0, c = 0;
  #pragma unroll
  for (int q2 = 15; q2 >= 0; --q2) {
    if (j >= JBc[q2]) { qt = q2; c = j - JBc[q2]; break; }
  }
  const int nt  = 2 * qt + 2;
  const int lo  = CHUNK * c;
  const int hiT = min(lo + CHUNK, nt);
  const int nc  = JBc[qt + 1] - JBc[qt];

  const float SCALE = 1.44269504088896f / sqrtf((float)DD);
  const char* KG = (const char*)Kbf + (size_t)h * SS * DD * 2;   // [t][d] bf16
  const char* VG = (const char*)VTg + (size_t)h * 32 * 16384;    // [tc][d][t']

  auto issueK = [&](int t0, int buf) {
    const char* gt = KG + (size_t)t0 * 256;
    char* lb = (char*)&Klds[buf][0] + wid * 4096;
    #pragma unroll
    for (int k2 = 0; k2 < 4; ++k2)
      gld16(gt + koff[k2], lb + k2 * 1024);
  };
  auto issueV = [&](int tc, int buf) {
    const char* gt = VG + (size_t)tc * 16384;
    char* lb = (char*)&VTlds[buf][0] + wid * 4096;
    #pragma unroll
    for (int k2 = 0; k2 < 4; ++k2)
      gld16(gt + voff[k2], lb + k2 * 1024);
  };

  const int qw = qt * QB + 32 * wid;   // wave's first q row
  const int qg = qw + q32;             // this lane's q row

  // ---- Q fragments (B operand): qf[ks] = Q[qg][16ks+8hi+0..7] * SCALE ----
  bf16x8 qf[8];
  {
    const float* qr = Q + ((size_t)qg * HH + h) * DD;
    #pragma unroll
    for (int ks = 0; ks < 8; ++ks) {
      float4 x = *(const float4*)&qr[16 * ks + 8 * hi];
      float4 y = *(const float4*)&qr[16 * ks + 8 * hi + 4];
      uint4 u;
      u.x = pk2(x.x * SCALE, x.y * SCALE);
      u.y = pk2(x.z * SCALE, x.w * SCALE);
      u.z = pk2(y.x * SCALE, y.y * SCALE);
      u.w = pk2(y.z * SCALE, y.w * SCALE);
      qf[ks] = __builtin_bit_cast(bf16x8, u);
    }
  }

  f32x16 acc[4];
  #pragma unroll
  for (int dt = 0; dt < 4; ++dt)
    #pragma unroll
    for (int e = 0; e < 16; ++e) acc[dt][e] = 0.f;
  float m = -1e30f, l = 0.f;

  // ---- prologue: DMA tile lo into buf0 ----
  issueK(lo * KVB, 0);
  issueV(lo, 0);
  int cur = 0;

  for (int itile = lo; itile < hiT; ++itile) {
    __syncthreads();             // drains DMAs -> buf[cur] resident; syncs readers
    const bool more = (itile + 1 < hiT);
    if (more) {                  // overlaps all compute below
      issueK((itile + 1) * KVB, cur ^ 1);
      issueV(itile + 1, cur ^ 1);
    }

    const int t0 = itile * KVB;
    const char* Kc = (const char*)&Klds[cur][0];
    const char* Vc = (const char*)&VTlds[cur][0];

    // ---- QK^T swapped, s0/s1 interleaved ----
    f32x16 s0, s1;
    #pragma unroll
    for (int e = 0; e < 16; ++e) { s0[e] = 0.f; s1[e] = 0.f; }
    __builtin_amdgcn_s_setprio(1);
    #pragma unroll
    for (int ks = 0; ks < 8; ++ks) {
      bf16x8 a0 = *(const bf16x8*)(Kc + ((q32 * 256 + 32 * ks + 16 * hi) ^ kxk));
      s0 = __builtin_amdgcn_mfma_f32_32x32x16_bf16(a0, qf[ks], s0, 0, 0, 0);
      bf16x8 a1 = *(const bf16x8*)(Kc + (((q32 + 32) * 256 + 32 * ks + 16 * hi) ^ kxk));
      s1 = __builtin_amdgcn_mfma_f32_32x32x16_bf16(a1, qf[ks], s1, 0, 0, 0);
    }
    __builtin_amdgcn_s_setprio(0);

    // ---- causal mask ----
    if (t0 + KVB - 1 > qw) {
      #pragma unroll
      for (int e = 0; e < 16; ++e) {
        int tloc = (e & 3) + 8 * (e >> 2) + 4 * hi;
        if (t0 + tloc > qg)      s0[e] = -INFINITY;
        if (t0 + 32 + tloc > qg) s1[e] = -INFINITY;
      }
    }

    // ---- online softmax: tree reductions + defer-max ----
    float tmx[8];
    #pragma unroll
    for (int e = 0; e < 8; ++e)
      tmx[e] = fmaxf(fmaxf(s0[e], s0[e + 8]), fmaxf(s1[e], s1[e + 8]));
    #pragma unroll
    for (int st = 4; st >= 1; st >>= 1)
      #pragma unroll
      for (int e = 0; e < st; ++e) tmx[e] = fmaxf(tmx[e], tmx[e + st]);
    float mr = fmaxf(tmx[0], __shfl_xor(tmx[0], 32));

    if (!__all(mr <= m + 8.0f)) {
      float mn = fmaxf(m, mr);
      float corr = exp2f(m - mn);
      m = mn;
      l *= corr;
      #pragma unroll
      for (int dt = 0; dt < 4; ++dt)
        #pragma unroll
        for (int e = 0; e < 16; ++e) acc[dt][e] *= corr;
    }

    float ts[8];
    #pragma unroll
    for (int e = 0; e < 8; ++e) ts[e] = 0.f;
    #pragma unroll
    for (int e = 0; e < 16; ++e) {
      float p0 = exp2f(s0[e] - m); s0[e] = p0;
      float p1 = exp2f(s1[e] - m); s1[e] = p1;
      ts[e & 7] += p0 + p1;
    }
    #pragma unroll
    for (int st = 4; st >= 1; st >>= 1)
      #pragma unroll
      for (int e = 0; e < st; ++e) ts[e] += ts[e + st];
    float ps = ts[0] + __shfl_xor(ts[0], 32);
    l += ps;

    // ---- P -> bf16 B-fragments (cvt_pk pairs + lane<->lane+32 exchange) ----
    uint4 paf[4];
    #pragma unroll
    for (int tk = 0; tk < 4; ++tk) {
      float p0,p1,p2,p3,p4,p5,p6,p7;
      if (tk == 0) { p0=s0[0];p1=s0[1];p2=s0[2];p3=s0[3];p4=s0[4];p5=s0[5];p6=s0[6];p7=s0[7]; }
      else if (tk == 1) { p0=s0[8];p1=s0[9];p2=s0[10];p3=s0[11];p4=s0[12];p5=s0[13];p6=s0[14];p7=s0[15]; }
      else if (tk == 2) { p0=s1[0];p1=s1[1];p2=s1[2];p3=s1[3];p4=s1[4];p5=s1[5];p6=s1[6];p7=s1[7]; }
      else { p0=s1[8];p1=s1[9];p2=s1[10];p3=s1[11];p4=s1[12];p5=s1[13];p6=s1[14];p7=s1[15]; }
      uint A0 = pk2(p0, p1), A1 = pk2(p2, p3);
      uint B0 = pk2(p4, p5), B1 = pk2(p6, p7);
      uint x0 = hi ? A0 : B0, x1 = hi ? A1 : B1;
      uint r0 = (uint)__shfl_xor((int)x0, 32);
      uint r1 = (uint)__shfl_xor((int)x1, 32);
      paf[tk].x = hi ? r0 : A0;
      paf[tk].y = hi ? r1 : A1;
      paf[tk].z = hi ? B0 : r0;
      paf[tk].w = hi ? B1 : r1;
    }

    // ---- PV: tk outer / dt inner ----
    __builtin_amdgcn_s_setprio(1);
    #pragma unroll
    for (int tk = 0; tk < 4; ++tk) {
      bf16x8 pb = __builtin_bit_cast(bf16x8, paf[tk]);
      #pragma unroll
      for (int dt = 0; dt < 4; ++dt) {
        bf16x8 va = *(const bf16x8*)(Vc +
                      (((dt * 32 + q32) * 128 + 32 * tk + 16 * hi) ^ kxv));
        acc[dt] = __builtin_amdgcn_mfma_f32_32x32x16_bf16(va, pb, acc[dt], 0, 0, 0);
      }
    }
    __builtin_amdgcn_s_setprio(0);

    cur ^= 1;
  }

  // ---- epilogue ----
  const int row = 32 * wid + q32;
  if (nc == 1) {
    float invl = 1.0f / l;
    float* op = O + ((size_t)(qt * QB + row) * HH + h) * DD;
    #pragma unroll
    for (int dt = 0; dt < 4; ++dt) {
      #pragma unroll
      for (int rq = 0; rq < 4; ++rq) {
        int d = 32 * dt + 8 * rq + 4 * hi;
        float4 x = make_float4(acc[dt][4 * rq + 0] * invl, acc[dt][4 * rq + 1] * invl,
                               acc[dt][4 * rq + 2] * invl, acc[dt][4 * rq + 3] * invl);
        *(float4*)&op[d] = x;
      }
    }
  } else {
    ushort* po = PO + (size_t)bx * (QB * DD);
    #pragma unroll
    for (int dt = 0; dt < 4; ++dt) {
      #pragma unroll
      for (int rq = 0; rq < 4; ++rq) {
        int d = 32 * dt + 8 * rq + 4 * hi;
        uint2 w;
        w.x = pk2(acc[dt][4 * rq + 0], acc[dt][4 * rq + 1]);
        w.y = pk2(acc[dt][4 * rq + 2], acc[dt][4 * rq + 3]);
        *(uint2*)&po[row * DD + d] = w;
      }
    }
    if (hi == 0) {
      PM[(size_t)bx * QB + row] = m;
      PL[(size_t)bx * QB + row] = l;
    }
  }
}

// ---------------------------------------------------------------------------
// Merge 2-5 partials per (h, qt) for qt >= 3.
// ---------------------------------------------------------------------------
__global__ __launch_bounds__(256, 2)
void attn_merge(const ushort* __restrict__ PO, const float* __restrict__ PM,
                const float* __restrict__ PL, float* __restrict__ O) {
  const int bx  = blockIdx.x;      // 208 = 13 qt * 16 h
  const int h   = bx & 15;
  const int qt  = 3 + (bx >> 4);   // 3..15
  const int tid = threadIdx.x;
  const int r   = tid >> 1;        // 0..127
  const int dh  = (tid & 1) * 64;

  const int base = JBc[qt];
  const int nc   = JBc[qt + 1] - JBc[qt];

  float M = -1e30f;
  for (int cc = 0; cc < nc; ++cc) {
    int slot = (base + cc) * 16 + h;
    M = fmaxf(M, PM[(size_t)slot * QB + r]);
  }
  float L = 0.f;
  float o[64];
  #pragma unroll
  for (int k2 = 0; k2 < 64; ++k2) o[k2] = 0.f;
  for (int cc = 0; cc < nc; ++cc) {
    int slot = (base + cc) * 16 + h;
    float w = exp2f(PM[(size_t)slot * QB + r] - M);
    L += PL[(size_t)slot * QB + r] * w;
    const ushort* src = PO + (size_t)slot * (QB * DD) + r * DD + dh;
    #pragma unroll
    for (int k4 = 0; k4 < 16; ++k4) {
      ushort4 u = *(const ushort4*)&src[4 * k4];
      o[4*k4+0] += bf2f(u.x) * w;
      o[4*k4+1] += bf2f(u.y) * w;
      o[4*k4+2] += bf2f(u.z) * w;
      o[4*k4+3] += bf2f(u.w) * w;
    }
  }
  float inv = 1.0f / L;
  float* op = O + ((size_t)(qt * QB + r) * HH + h) * DD + dh;
  #pragma unroll
  for (int k4 = 0; k4 < 16; ++k4) {
    float4 x = make_float4(o[4*k4]*inv, o[4*k4+1]*inv, o[4*k4+2]*inv, o[4*k4+3]*inv);
    *(float4*)&op[4 * k4] = x;
  }
}

extern "C" void kernel_launch(void* const* d_in, const int* in_sizes, int n_in,
                              void* d_out, int out_size, void* d_ws, size_t ws_size,
                              hipStream_t stream) {
  const float* Q = (const float*)d_in[0];
  const float* K = (const float*)d_in[1];
  const float* V = (const float*)d_in[2];
  float* O = (float*)d_out;

  const size_t kv_elems = (size_t)HH * SS * DD;          // 4,194,304 ushorts each
  ushort* Kbf = (ushort*)d_ws;                           // 8.4 MB
  ushort* VTg = Kbf + kv_elems;                          // 8.4 MB
  ushort* PO  = VTg + kv_elems;                          // 736*16384 bf16 = 24.1 MB
  float*  PM  = (float*)(PO + (size_t)(NJ * 16) * QB * DD);
  float*  PL  = PM + (size_t)(NJ * 16) * QB;

  prep_kv<<<dim3(HH * (SS / 64)), 256, 0, stream>>>(K, V, Kbf, VTg);
  attn_fwd<<<dim3(NJ * 16), 256, 0, stream>>>(Q, Kbf, VTg, O, PO, PM, PL);
  attn_merge<<<dim3(13 * 16), 256, 0, stream>>>(PO, PM, PL, O);
}

// Round 15
// 77.455 us; speedup vs baseline: 2.4354x; 1.0156x over previous
//
#include <hip/hip_runtime.h>
#include <hip/hip_bf16.h>
#include <math.h>

#define SS 2048
#define HH 16
#define DD 128
#define HD (HH*DD)
#define QB 128          // q-rows per block (4 waves x 32)
#define KVB 64          // kv-tile
#define NJ 38           // per-head jobs

typedef __attribute__((ext_vector_type(8))) short bf16x8;
typedef __attribute__((ext_vector_type(16))) float f32x16;

__device__ __forceinline__ ushort f2bf(float f) {
  __hip_bfloat16 h = __float2bfloat16(f);
  return __builtin_bit_cast(ushort, h);
}
__device__ __forceinline__ uint pk2(float a, float b) {   // low=a, high=b
  return ((uint)f2bf(b) << 16) | (uint)f2bf(a);
}
__device__ __forceinline__ float bf2f(ushort u) {
  uint x = ((uint)u) << 16;
  return __builtin_bit_cast(float, x);
}
__device__ __forceinline__ void gld16(const void* g, void* l) {
  __builtin_amdgcn_global_load_lds(
      (const __attribute__((address_space(1))) void*)g,
      (__attribute__((address_space(3))) void*)l, 16, 0, 0);
}

// nc(qt) = ceil((2qt+2)/9): {1,1,1,1,2,2,2,2,2,3,3,3,3,4,4,4}; JB2 = prefix
__constant__ const int JB2c[17] = {0,1,2,3,4,6,8,10,12,14,17,20,23,26,30,34,38};

// ---------------------------------------------------------------------------
// Prep (V only): V fp32 [t][h][d] -> bf16 VTg [h][tc][d][t'] (tile-blocked)
// ---------------------------------------------------------------------------
__global__ __launch_bounds__(256, 4)
void prep_v(const float* __restrict__ V, ushort* __restrict__ VTg) {
  __shared__ ushort Vlds[64][136];
  const int tid = threadIdx.x;
  const int h  = blockIdx.x & 15;
  const int tc = blockIdx.x >> 4;
  const int t0 = tc * 64;

  #pragma unroll
  for (int j = 0; j < 2; ++j) {
    int li = tid + j * 256;
    int t  = li >> 3;
    int c  = (li & 7) << 4;
    const float* src = V + ((size_t)(t0 + t) * HH + h) * DD + c;
    #pragma unroll
    for (int q = 0; q < 4; ++q) {
      float4 x = *(const float4*)(src + 4 * q);
      ushort4 w; w.x = f2bf(x.x); w.y = f2bf(x.y); w.z = f2bf(x.z); w.w = f2bf(x.w);
      *(ushort4*)&Vlds[t][c + 4 * q] = w;
    }
  }
  __syncthreads();

  #pragma unroll
  for (int j = 0; j < 2; ++j) {
    int li  = tid + j * 256;
    int d   = li >> 2;
    int t16 = (li & 3) << 4;
    ushort tmp[16];
    #pragma unroll
    for (int k = 0; k < 16; ++k) tmp[k] = Vlds[t16 + k][d];
    ushort* dst = VTg + (((size_t)h * 32 + tc) * DD + d) * 64 + t16;
    *(uint4*)dst       = *(uint4*)&tmp[0];
    *(uint4*)(dst + 8) = *(uint4*)&tmp[8];
  }
}

// ---------------------------------------------------------------------------
// Flash attention. Job decode: jrev = 37-(bx>>4) -> (qt,c) via JB2, so LOW
// blockIdx = LONGEST jobs (qt=15 first): dispatch-order packing, stragglers
// are tiny backfill jobs. Balanced chunks lo=(c*nt)/nc (all partial jobs
// 5-9 tiles). K: fp32 reg-stage + cvt + swizzled ds_write (R10 path), dbuf.
// V: bf16 DMA via global_load_lds from VTg (R14 path), dbuf. ONE barrier
// per tile. launch_bounds(256,2) - this is a 2-blocks/CU design (R11-R13
// law: tighter caps trade spill for occupancy at a net loss).
// ---------------------------------------------------------------------------
__global__ __launch_bounds__(256, 2)
void attn_fwd(const float* __restrict__ Q, const float* __restrict__ K,
              const ushort* __restrict__ VTg, float* __restrict__ O,
              ushort* __restrict__ PO, float* __restrict__ PM,
              float* __restrict__ PL) {
  __shared__ alignas(16) ushort Klds[2][KVB * DD];   // 2 x 16 KB
  __shared__ alignas(16) ushort VTlds[2][DD * KVB];  // 2 x 16 KB

  const int tid  = threadIdx.x;
  const int lane = tid & 63;
  const int wid  = tid >> 6;       // 0..3
  const int q32  = lane & 31;
  const int hi   = lane >> 5;
  const int kxk  = (q32 & 15) << 4;                        // K read swizzle
  const int kxv  = ((q32 & 7) << 4) ^ ((q32 & 8) << 1);    // V read swizzle

  // V-DMA per-lane source offsets (pre-swizzle)
  int voff[4];
  #pragma unroll
  for (int k2 = 0; k2 < 4; ++k2) {
    int b = wid * 4096 + k2 * 1024 + 16 * lane;
    int d = b >> 7;
    voff[k2] = b ^ (((d & 7) << 4) ^ ((d & 8) << 1));
  }

  const int bx = blockIdx.x;         // 0..607
  const int h  = bx & 15;
  const int jrev = (NJ - 1) - (bx >> 4);   // long jobs at low bx
  int qt = 0, c = 0;
  #pragma unroll
  for (int q2 = 15; q2 >= 0; --q2) {
    if (jrev >= JB2c[q2]) { qt = q2; c = jrev - JB2c[q2]; break; }
  }
  const int nt  = 2 * qt + 2;
  const int nc  = JB2c[qt + 1] - JB2c[qt];
  const int lo  = (c * nt) / nc;
  const int hiT = ((c + 1) * nt) / nc;

  const float SCALE = 1.44269504088896f / sqrtf((float)DD);
  const float* Kb = K + (size_t)h * DD;
  const char*  VG = (const char*)VTg + (size_t)h * 32 * 16384;

  uint4 kreg[4];
  auto loadK = [&](int t0) {
    #pragma unroll
    for (int it = 0; it < 4; ++it) {
      int e = tid + it * 256;
      int row = e >> 4, col = (e & 15) * 8;
      const float* src = &Kb[(size_t)(t0 + row) * HD + col];
      float4 a = *(const float4*)src;
      float4 b = *(const float4*)(src + 4);
      kreg[it].x = pk2(a.x, a.y); kreg[it].y = pk2(a.z, a.w);
      kreg[it].z = pk2(b.x, b.y); kreg[it].w = pk2(b.z, b.w);
    }
  };
  auto stageK = [&](int buf) {
    #pragma unroll
    for (int it = 0; it < 4; ++it) {
      int e = tid + it * 256;
      *(uint4*)((char*)&Klds[buf][0] + ((e * 16) ^ (e & 0xF0))) = kreg[it];
    }
  };
  auto issueV = [&](int tc, int buf) {
    const char* gt = VG + (size_t)tc * 16384;
    char* lb = (char*)&VTlds[buf][0] + wid * 4096;
    #pragma unroll
    for (int k2 = 0; k2 < 4; ++k2)
      gld16(gt + voff[k2], lb + k2 * 1024);
  };

  const int qw = qt * QB + 32 * wid;   // wave's first q row
  const int qg = qw + q32;             // this lane's q row

  // ---- Q fragments (B operand): qf[ks] = Q[qg][16ks+8hi+0..7] * SCALE ----
  bf16x8 qf[8];
  {
    const float* qr = Q + ((size_t)qg * HH + h) * DD;
    #pragma unroll
    for (int ks = 0; ks < 8; ++ks) {
      float4 x = *(const float4*)&qr[16 * ks + 8 * hi];
      float4 y = *(const float4*)&qr[16 * ks + 8 * hi + 4];
      uint4 u;
      u.x = pk2(x.x * SCALE, x.y * SCALE);
      u.y = pk2(x.z * SCALE, x.w * SCALE);
      u.z = pk2(y.x * SCALE, y.y * SCALE);
      u.w = pk2(y.z * SCALE, y.w * SCALE);
      qf[ks] = __builtin_bit_cast(bf16x8, u);
    }
  }

  f32x16 acc[4];
  #pragma unroll
  for (int dt = 0; dt < 4; ++dt)
    #pragma unroll
    for (int e = 0; e < 16; ++e) acc[dt][e] = 0.f;
  float m = -1e30f, l = 0.f;

  // ---- prologue: tile lo -> buf0 ----
  loadK(lo * KVB);
  issueV(lo, 0);
  stageK(0);
  int cur = 0;

  for (int itile = lo; itile < hiT; ++itile) {
    __syncthreads();             // V DMA drained + K writes visible + readers synced
    const bool more = (itile + 1 < hiT);
    if (more) {
      issueV(itile + 1, cur ^ 1);     // async DMA overlaps everything below
      loadK((itile + 1) * KVB);       // fp32 loads land during QK^T+softmax
    }

    const int t0 = itile * KVB;
    const char* Kc = (const char*)&Klds[cur][0];
    const char* Vc = (const char*)&VTlds[cur][0];

    // ---- QK^T swapped, s0/s1 interleaved ----
    f32x16 s0, s1;
    #pragma unroll
    for (int e = 0; e < 16; ++e) { s0[e] = 0.f; s1[e] = 0.f; }
    __builtin_amdgcn_s_setprio(1);
    #pragma unroll
    for (int ks = 0; ks < 8; ++ks) {
      bf16x8 a0 = *(const bf16x8*)(Kc + ((q32 * 256 + 32 * ks + 16 * hi) ^ kxk));
      s0 = __builtin_amdgcn_mfma_f32_32x32x16_bf16(a0, qf[ks], s0, 0, 0, 0);
      bf16x8 a1 = *(const bf16x8*)(Kc + (((q32 + 32) * 256 + 32 * ks + 16 * hi) ^ kxk));
      s1 = __builtin_amdgcn_mfma_f32_32x32x16_bf16(a1, qf[ks], s1, 0, 0, 0);
    }
    __builtin_amdgcn_s_setprio(0);

    // ---- causal mask ----
    if (t0 + KVB - 1 > qw) {
      #pragma unroll
      for (int e = 0; e < 16; ++e) {
        int tloc = (e & 3) + 8 * (e >> 2) + 4 * hi;
        if (t0 + tloc > qg)      s0[e] = -INFINITY;
        if (t0 + 32 + tloc > qg) s1[e] = -INFINITY;
      }
    }

    // ---- online softmax: tree reductions + defer-max ----
    float tmx[8];
    #pragma unroll
    for (int e = 0; e < 8; ++e)
      tmx[e] = fmaxf(fmaxf(s0[e], s0[e + 8]), fmaxf(s1[e], s1[e + 8]));
    #pragma unroll
    for (int st = 4; st >= 1; st >>= 1)
      #pragma unroll
      for (int e = 0; e < st; ++e) tmx[e] = fmaxf(tmx[e], tmx[e + st]);
    float mr = fmaxf(tmx[0], __shfl_xor(tmx[0], 32));

    if (!__all(mr <= m + 8.0f)) {
      float mn = fmaxf(m, mr);
      float corr = exp2f(m - mn);
      m = mn;
      l *= corr;
      #pragma unroll
      for (int dt = 0; dt < 4; ++dt)
        #pragma unroll
        for (int e = 0; e < 16; ++e) acc[dt][e] *= corr;
    }

    float ts[8];
    #pragma unroll
    for (int e = 0; e < 8; ++e) ts[e] = 0.f;
    #pragma unroll
    for (int e = 0; e < 16; ++e) {
      float p0 = exp2f(s0[e] - m); s0[e] = p0;
      float p1 = exp2f(s1[e] - m); s1[e] = p1;
      ts[e & 7] += p0 + p1;
    }
    #pragma unroll
    for (int st = 4; st >= 1; st >>= 1)
      #pragma unroll
      for (int e = 0; e < st; ++e) ts[e] += ts[e + st];
    float ps = ts[0] + __shfl_xor(ts[0], 32);
    l += ps;

    // ---- P -> bf16 B-fragments (cvt_pk pairs + lane<->lane+32 exchange) ----
    uint4 paf[4];
    #pragma unroll
    for (int tk = 0; tk < 4; ++tk) {
      float p0,p1,p2,p3,p4,p5,p6,p7;
      if (tk == 0) { p0=s0[0];p1=s0[1];p2=s0[2];p3=s0[3];p4=s0[4];p5=s0[5];p6=s0[6];p7=s0[7]; }
      else if (tk == 1) { p0=s0[8];p1=s0[9];p2=s0[10];p3=s0[11];p4=s0[12];p5=s0[13];p6=s0[14];p7=s0[15]; }
      else if (tk == 2) { p0=s1[0];p1=s1[1];p2=s1[2];p3=s1[3];p4=s1[4];p5=s1[5];p6=s1[6];p7=s1[7]; }
      else { p0=s1[8];p1=s1[9];p2=s1[10];p3=s1[11];p4=s1[12];p5=s1[13];p6=s1[14];p7=s1[15]; }
      uint A0 = pk2(p0, p1), A1 = pk2(p2, p3);
      uint B0 = pk2(p4, p5), B1 = pk2(p6, p7);
      uint x0 = hi ? A0 : B0, x1 = hi ? A1 : B1;
      uint r0 = (uint)__shfl_xor((int)x0, 32);
      uint r1 = (uint)__shfl_xor((int)x1, 32);
      paf[tk].x = hi ? r0 : A0;
      paf[tk].y = hi ? r1 : A1;
      paf[tk].z = hi ? B0 : r0;
      paf[tk].w = hi ? B1 : r1;
    }

    // ---- stage next K tile (loads have landed by now) ----
    if (more) stageK(cur ^ 1);

    // ---- PV: tk outer / dt inner ----
    __builtin_amdgcn_s_setprio(1);
    #pragma unroll
    for (int tk = 0; tk < 4; ++tk) {
      bf16x8 pb = __builtin_bit_cast(bf16x8, paf[tk]);
      #pragma unroll
      for (int dt = 0; dt < 4; ++dt) {
        bf16x8 va = *(const bf16x8*)(Vc +
                      (((dt * 32 + q32) * 128 + 32 * tk + 16 * hi) ^ kxv));
        acc[dt] = __builtin_amdgcn_mfma_f32_32x32x16_bf16(va, pb, acc[dt], 0, 0, 0);
      }
    }
    __builtin_amdgcn_s_setprio(0);

    cur ^= 1;
  }

  // ---- epilogue ----
  const int row = 32 * wid + q32;
  if (nc == 1) {
    float invl = 1.0f / l;
    float* op = O + ((size_t)(qt * QB + row) * HH + h) * DD;
    #pragma unroll
    for (int dt = 0; dt < 4; ++dt) {
      #pragma unroll
      for (int rq = 0; rq < 4; ++rq) {
        int d = 32 * dt + 8 * rq + 4 * hi;
        float4 x = make_float4(acc[dt][4 * rq + 0] * invl, acc[dt][4 * rq + 1] * invl,
                               acc[dt][4 * rq + 2] * invl, acc[dt][4 * rq + 3] * invl);
        *(float4*)&op[d] = x;
      }
    }
  } else {
    ushort* po = PO + (size_t)bx * (QB * DD);
    #pragma unroll
    for (int dt = 0; dt < 4; ++dt) {
      #pragma unroll
      for (int rq = 0; rq < 4; ++rq) {
        int d = 32 * dt + 8 * rq + 4 * hi;
        uint2 w;
        w.x = pk2(acc[dt][4 * rq + 0], acc[dt][4 * rq + 1]);
        w.y = pk2(acc[dt][4 * rq + 2], acc[dt][4 * rq + 3]);
        *(uint2*)&po[row * DD + d] = w;
      }
    }
    if (hi == 0) {
      PM[(size_t)bx * QB + row] = m;
      PL[(size_t)bx * QB + row] = l;
    }
  }
}

// ---------------------------------------------------------------------------
// Merge 2-4 partials per (h, qt) for qt >= 4.
// slot(h,qt,c) = h + 16*(NJ-1 - (JB2[qt]+c))
// ---------------------------------------------------------------------------
__global__ __launch_bounds__(256, 2)
void attn_merge(const ushort* __restrict__ PO, const float* __restrict__ PM,
                const float* __restrict__ PL, float* __restrict__ O) {
  const int bx  = blockIdx.x;      // 192 = 12 qt * 16 h
  const int h   = bx & 15;
  const int qt  = 4 + (bx >> 4);   // 4..15
  const int tid = threadIdx.x;
  const int r   = tid >> 1;        // 0..127
  const int dh  = (tid & 1) * 64;

  const int nc = JB2c[qt + 1] - JB2c[qt];

  float M = -1e30f;
  for (int cc = 0; cc < nc; ++cc) {
    int slot = h + 16 * ((NJ - 1) - (JB2c[qt] + cc));
    M = fmaxf(M, PM[(size_t)slot * QB + r]);
  }
  float L = 0.f;
  float o[64];
  #pragma unroll
  for (int k2 = 0; k2 < 64; ++k2) o[k2] = 0.f;
  for (int cc = 0; cc < nc; ++cc) {
    int slot = h + 16 * ((NJ - 1) - (JB2c[qt] + cc));
    float w = exp2f(PM[(size_t)slot * QB + r] - M);
    L += PL[(size_t)slot * QB + r] * w;
    const ushort* src = PO + (size_t)slot * (QB * DD) + r * DD + dh;
    #pragma unroll
    for (int k4 = 0; k4 < 16; ++k4) {
      ushort4 u = *(const ushort4*)&src[4 * k4];
      o[4*k4+0] += bf2f(u.x) * w;
      o[4*k4+1] += bf2f(u.y) * w;
      o[4*k4+2] += bf2f(u.z) * w;
      o[4*k4+3] += bf2f(u.w) * w;
    }
  }
  float inv = 1.0f / L;
  float* op = O + ((size_t)(qt * QB + r) * HH + h) * DD + dh;
  #pragma unroll
  for (int k4 = 0; k4 < 16; ++k4) {
    float4 x = make_float4(o[4*k4]*inv, o[4*k4+1]*inv, o[4*k4+2]*inv, o[4*k4+3]*inv);
    *(float4*)&op[4 * k4] = x;
  }
}

extern "C" void kernel_launch(void* const* d_in, const int* in_sizes, int n_in,
                              void* d_out, int out_size, void* d_ws, size_t ws_size,
                              hipStream_t stream) {
  const float* Q = (const float*)d_in[0];
  const float* K = (const float*)d_in[1];
  const float* V = (const float*)d_in[2];
  float* O = (float*)d_out;

  const size_t kv_elems = (size_t)HH * SS * DD;          // 4,194,304 ushorts
  ushort* VTg = (ushort*)d_ws;                           // 8.4 MB
  ushort* PO  = VTg + kv_elems;                          // 608*16384 bf16 = 19.9 MB
  float*  PM  = (float*)(PO + (size_t)(NJ * 16) * QB * DD);
  float*  PL  = PM + (size_t)(NJ * 16) * QB;

  prep_v<<<dim3(HH * (SS / 64)), 256, 0, stream>>>(V, VTg);
  attn_fwd<<<dim3(NJ * 16), 256, 0, stream>>>(Q, K, VTg, O, PO, PM, PL);
  attn_merge<<<dim3(12 * 16), 256, 0, stream>>>(PO, PM, PL, O);
}